// Round 10
// baseline (284.534 us; speedup 1.0000x reference)
//
#include <hip/hip_runtime.h>
#include <hip/hip_bf16.h>
#include <math.h>

#define E_EDGES 500000
#define PI_F 3.14159265358979323846f
#define TWOPI_F 6.28318530717958647692f

typedef __attribute__((ext_vector_type(4))) float f32x4;
typedef __attribute__((ext_vector_type(8))) short s16x8;

static __device__ __forceinline__ short f2bf(float x) {
    __hip_bfloat16 h = __float2bfloat16(x);
    return __builtin_bit_cast(short, h);
}

// ---------------- prep: W1/W2 -> bf16 fragment-slot layout in ws -------------
// Per d: 24 slots x 128 s16x8 (49152 B), contiguous in stage order:
//   slots 0..7   : W1^T  (staged to slabA, m1)
//   slots 8..15  : W2^T ks=0,1 (staged to slabB, m2 first half)
//   slots 16..23 : W2^T ks=2,3 (staged to slabA after m1, m2 second half)
// Entry j elems: bf16 of W[(kb+i)*128+j] (i=0..3) and W[(kb+16+i)*128+j] (4..7).
__global__ void rape_prep_kernel(const float* __restrict__ W1,
                                 const float* __restrict__ W2,
                                 s16x8* __restrict__ ws)
{
    const int d  = blockIdx.x / 24;
    const int sg = blockIdx.x % 24;
    const int j  = threadIdx.x;            // 0..127
    s16x8 v;
    if (sg < 8) {
        const float* W1d = W1 + (size_t)d * 65 * 128;
        const int kb = (sg >> 2) * 32 + (sg & 3) * 4;
        #pragma unroll
        for (int i = 0; i < 4; ++i) {
            v[i]     = f2bf(W1d[(kb + i) * 128 + j]);
            v[i + 4] = f2bf(W1d[(kb + 16 + i) * 128 + j]);
        }
    } else {
        const int sg2 = sg - 8;
        const float* W2d = W2 + (size_t)d * 128 * 128;
        const int kb = (sg2 >> 2) * 32 + (sg2 & 3) * 4;
        #pragma unroll
        for (int i = 0; i < 4; ++i) {
            v[i]     = f2bf(W2d[(kb + i) * 128 + j]);
            v[i + 4] = f2bf(W2d[(kb + 16 + i) * 128 + j]);
        }
    }
    ws[(size_t)d * 24 * 128 + sg * 128 + j] = v;
}

// ---------------- main fused kernel ------------------------------------------
// R5 math (verified 244 us) with split-slab staging: resident slab shrinks
// 48->32 KB so LDS = 49.3 KB -> 3 blocks/CU (12 waves, +50% latency hiding).
// Per d: stage W1->A + W2a->B | trig; bar; m1(A); LN->pb regs; bar;
//        stage W2b->A | m2a(B); bar; m2b(A).
__global__ __launch_bounds__(256, 3)
void rape_mfma10_kernel(const float* __restrict__ source,
                        const float* __restrict__ target,
                        const int*   __restrict__ edge,
                        const float* __restrict__ freqs,
                        const float* __restrict__ W1,
                        const float* __restrict__ b1,
                        const float* __restrict__ ln_w,
                        const float* __restrict__ ln_b,
                        const float* __restrict__ b2,
                        const s16x8* __restrict__ wsg,
                        float* __restrict__ out)
{
    __shared__ s16x8 slabA[8 * 128];      // 16384 B: W1, then W2 ks2-3
    __shared__ s16x8 slabB[8 * 128];      // 16384 B: W2 ks0-1
    __shared__ float feat_s[6][128];      // 3072 B
    __shared__ float b1_s[768];           // [d][j]
    __shared__ float lnw_s[768];
    __shared__ float lnb_s[768];
    __shared__ float w164_s[768];         // W1[d][64][j]
    __shared__ float freq_s[192];         // -> total 49280 B (3 blocks/CU)

    const int tid   = threadIdx.x;
    const int lane  = tid & 63;
    const int wv    = tid >> 6;           // wave 0..3
    const int c     = lane & 15;          // edge-col within 16
    const int g     = lane >> 4;          // k-group 0..3
    const int ebase = blockIdx.x * 128;

    // ---- one-time staging: params + features ----
    for (int i = tid; i < 768; i += 256) {
        b1_s[i]   = b1[i];
        lnw_s[i]  = ln_w[i];
        lnb_s[i]  = ln_b[i];
        w164_s[i] = W1[((size_t)(i >> 7) * 65 + 64) * 128 + (i & 127)];
    }
    if (tid < 192) freq_s[tid] = freqs[tid];

    if (tid < 128) {
        int ec = ebase + tid; if (ec >= E_EDGES) ec = E_EDGES - 1;
        int si = edge[ec];
        int ti = edge[E_EDGES + ec];
        const float* S = source + (size_t)si * 5;
        const float* T = target + (size_t)ti * 5;
        float spx = S[0], spy = S[1], shd = S[2], ss = S[3];
        float tpx = T[0], tpy = T[1], thd = T[2], ts = T[3];
        float dx = spx - tpx, dy = spy - tpy;
        float dist = sqrtf(dx * dx + dy * dy);
        float ic  = dist < 3.0f ? 1.0f : 0.0f;
        float inv = dist > 0.0f ? 1.0f / dist : 0.0f;
        float ca  = dist > 0.0f ? dx * inv : 1.0f;   // cos(atan2), atan2(0,0)=0
        float sa  = dy * inv;
        float a = shd - thd + PI_F;
        float r = fmodf(a, TWOPI_F);
        r = r < 0.0f ? r + TWOPI_F : r;
        float dh = r - PI_F;
        float tc = ts * (cosf(thd) * ca + sinf(thd) * sa);
        float sc = ss * (cosf(shd) * ca + sinf(shd) * sa);
        feat_s[0][tid] = dx; feat_s[1][tid] = dy; feat_s[2][tid] = dh;
        feat_s[3][tid] = ic; feat_s[4][tid] = tc; feat_s[5][tid] = sc;
    }

    // ---- acc init: sum_d b2[d][g'],  g' = 4g + q + 16gt (global, once) ----
    f32x4 acc[2][8];
    #pragma unroll
    for (int gt = 0; gt < 8; ++gt) {
        f32x4 s = {0.f, 0.f, 0.f, 0.f};
        #pragma unroll
        for (int d = 0; d < 6; ++d)
            s += *(const f32x4*)(b2 + d * 128 + gt * 16 + g * 4);
        acc[0][gt] = s; acc[1][gt] = s;
    }

    for (int d = 0; d < 6; ++d) {
        __syncthreads();   // (a) prev d's slab reads done; d=0: init writes visible

        // ---- stage1: W1 -> slabA (16 KB), W2 ks0-1 -> slabB (16 KB) ----
        {
            const char* gsrc = (const char*)(wsg + (size_t)d * 24 * 128);
            #pragma unroll
            for (int it = 0; it < 4; ++it) {
                const int off = tid * 16 + it * 4096;
                __builtin_amdgcn_global_load_lds(
                    (const __attribute__((address_space(1))) unsigned int*)(gsrc + off),
                    (__attribute__((address_space(3))) unsigned int*)((char*)slabA + off),
                    16, 0, 0);
            }
            #pragma unroll
            for (int it = 0; it < 4; ++it) {
                const int off = tid * 16 + it * 4096;
                __builtin_amdgcn_global_load_lds(
                    (const __attribute__((address_space(1))) unsigned int*)(gsrc + 16384 + off),
                    (__attribute__((address_space(3))) unsigned int*)((char*)slabB + off),
                    16, 0, 0);
            }
        }

        // ---- m1 B-frags from trig while staging flies ----
        // k = 32*ks + 4g + q + 16p ; elem i<4 -> p=0, i>=4 -> p=1
        s16x8 bfr[2][2];
        float xv[2];
        const f32x4 fq0 = *(const f32x4*)(freq_s + d * 32 + g * 4);
        const f32x4 fq1 = *(const f32x4*)(freq_s + d * 32 + 16 + g * 4);
        #pragma unroll
        for (int es = 0; es < 2; ++es) {
            const float x = feat_s[d][wv * 32 + es * 16 + c];
            xv[es] = x;
            s16x8 bc, bs;
            #pragma unroll
            for (int i = 0; i < 8; ++i) {
                const float f = (i < 4) ? fq0[i] : fq1[i - 4];
                const float t = x * f;
                const float tf = t - floorf(t);
                bc[i] = f2bf(__builtin_amdgcn_cosf(tf));  // cos(2*pi*t)
                bs[i] = f2bf(__builtin_amdgcn_sinf(tf));
            }
            bfr[es][0] = bc; bfr[es][1] = bs;
        }

        // ---- d1 init: b1 + x * W1[k=64] (fp32 passthrough, from LDS) ----
        f32x4 d1[2][8];
        #pragma unroll
        for (int jt = 0; jt < 8; ++jt) {
            const f32x4 bv  = *(const f32x4*)(b1_s   + d * 128 + jt * 16 + g * 4);
            const f32x4 wv4 = *(const f32x4*)(w164_s + d * 128 + jt * 16 + g * 4);
            d1[0][jt] = bv + xv[0] * wv4;
            d1[1][jt] = bv + xv[1] * wv4;
        }

        __syncthreads();   // (b) stage1 drained: slabA=W1, slabB=W2a ready

        // ---- m1: D1'[j][e] += sum_{k<64} W1^T[j][k] * X^T[k][e] ----
        #pragma unroll
        for (int jt = 0; jt < 8; ++jt) {
            const s16x8 a0 = slabA[(0 + g) * 128 + jt * 16 + c];
            const s16x8 a1 = slabA[(4 + g) * 128 + jt * 16 + c];
            #pragma unroll
            for (int es = 0; es < 2; ++es) {
                d1[es][jt] = __builtin_amdgcn_mfma_f32_16x16x32_bf16(a0, bfr[es][0], d1[es][jt], 0, 0, 0);
                d1[es][jt] = __builtin_amdgcn_mfma_f32_16x16x32_bf16(a1, bfr[es][1], d1[es][jt], 0, 0, 0);
            }
        }

        // ---- LayerNorm stats (lane holds j = 4g+q+16jt) ----
        float mu[2], rinv[2];
        #pragma unroll
        for (int es = 0; es < 2; ++es) {
            float s1 = 0.f, s2 = 0.f;
            #pragma unroll
            for (int jt = 0; jt < 8; ++jt)
                #pragma unroll
                for (int q = 0; q < 4; ++q) {
                    const float v = d1[es][jt][q];
                    s1 += v; s2 = fmaf(v, v, s2);
                }
            s1 += __shfl_xor(s1, 16); s1 += __shfl_xor(s1, 32);
            s2 += __shfl_xor(s2, 16); s2 += __shfl_xor(s2, 32);
            mu[es] = s1 * 0.0078125f;
            const float var = s2 * 0.0078125f - mu[es] * mu[es];
            rinv[es] = rsqrtf(var + 1e-5f);
        }
        // ---- LN apply + ReLU + pack -> pb registers ----
        s16x8 pb[2][4];
        #pragma unroll
        for (int ks = 0; ks < 4; ++ks) {
            #pragma unroll
            for (int p = 0; p < 2; ++p) {
                const int jt = 2 * ks + p;
                const f32x4 lw = *(const f32x4*)(lnw_s + d * 128 + jt * 16 + g * 4);
                const f32x4 lb = *(const f32x4*)(lnb_s + d * 128 + jt * 16 + g * 4);
                #pragma unroll
                for (int es = 0; es < 2; ++es) {
                    #pragma unroll
                    for (int q = 0; q < 4; ++q) {
                        float hv = (d1[es][jt][q] - mu[es]) * rinv[es];
                        hv = fmaf(hv, lw[q], lb[q]);
                        hv = fmaxf(hv, 0.f);
                        pb[es][ks][q + 4 * p] = f2bf(hv);   // m2 B-frag (k=j)
                    }
                }
            }
        }

        __syncthreads();   // (c) all waves done reading slabA (m1)

        // ---- stage2: W2 ks2-3 -> slabA (16 KB), overlapped with m2a ----
        {
            const char* gsrc = (const char*)(wsg + (size_t)d * 24 * 128) + 32768;
            #pragma unroll
            for (int it = 0; it < 4; ++it) {
                const int off = tid * 16 + it * 4096;
                __builtin_amdgcn_global_load_lds(
                    (const __attribute__((address_space(1))) unsigned int*)(gsrc + off),
                    (__attribute__((address_space(3))) unsigned int*)((char*)slabA + off),
                    16, 0, 0);
            }
        }

        // ---- m2a: ks 0..1 from slabB ----
        #pragma unroll
        for (int ks = 0; ks < 2; ++ks) {
            #pragma unroll
            for (int gt = 0; gt < 8; ++gt) {
                const s16x8 a = slabB[(ks * 4 + g) * 128 + gt * 16 + c];
                #pragma unroll
                for (int es = 0; es < 2; ++es)
                    acc[es][gt] = __builtin_amdgcn_mfma_f32_16x16x32_bf16(a, pb[es][ks], acc[es][gt], 0, 0, 0);
            }
        }

        __syncthreads();   // (d) stage2 drained: slabA=W2b ready

        // ---- m2b: ks 2..3 from slabA ----
        #pragma unroll
        for (int ks = 2; ks < 4; ++ks) {
            #pragma unroll
            for (int gt = 0; gt < 8; ++gt) {
                const s16x8 a = slabA[((ks - 2) * 4 + g) * 128 + gt * 16 + c];
                #pragma unroll
                for (int es = 0; es < 2; ++es)
                    acc[es][gt] = __builtin_amdgcn_mfma_f32_16x16x32_bf16(a, pb[es][ks], acc[es][gt], 0, 0, 0);
            }
        }
    }

    // ---- store: lane holds g' = 4g + q + 16gt of edges (wv*32 + es*16 + c) ----
    #pragma unroll
    for (int es = 0; es < 2; ++es) {
        const int e = ebase + wv * 32 + es * 16 + c;
        if (e < E_EDGES) {
            float* op = out + (size_t)e * 128 + g * 4;
            #pragma unroll
            for (int gt = 0; gt < 8; ++gt)
                *(f32x4*)(op + gt * 16) = acc[es][gt];
        }
    }
}

extern "C" void kernel_launch(void* const* d_in, const int* in_sizes, int n_in,
                              void* d_out, int out_size, void* d_ws, size_t ws_size,
                              hipStream_t stream) {
    const float* source = (const float*)d_in[0];
    const float* target = (const float*)d_in[1];
    const int*   edge   = (const int*)  d_in[2];
    const float* freqs  = (const float*)d_in[3];
    const float* W1     = (const float*)d_in[4];
    const float* b1     = (const float*)d_in[5];
    const float* ln_w   = (const float*)d_in[6];
    const float* ln_b   = (const float*)d_in[7];
    const float* W2     = (const float*)d_in[8];
    const float* b2     = (const float*)d_in[9];
    float* out = (float*)d_out;
    s16x8* wsg = (s16x8*)d_ws;    // needs 6*24*128*16 = 294912 B

    rape_prep_kernel<<<6 * 24, 128, 0, stream>>>(W1, W2, wsg);

    const int nblocks = (E_EDGES + 127) / 128;  // 3907
    rape_mfma10_kernel<<<nblocks, 256, 0, stream>>>(
        source, target, edge, freqs, W1, b1, ln_w, ln_b, b2, wsg, out);
}

// Round 11
// 258.918 us; speedup vs baseline: 1.0989x; 1.0989x over previous
//
#include <hip/hip_runtime.h>
#include <hip/hip_bf16.h>
#include <math.h>

#define E_EDGES 500000
#define PI_F 3.14159265358979323846f
#define TWOPI_F 6.28318530717958647692f

typedef __attribute__((ext_vector_type(4))) float f32x4;
typedef __attribute__((ext_vector_type(8))) short s16x8;
typedef __attribute__((ext_vector_type(4))) unsigned int u32x4;

static __device__ __forceinline__ short f2bf(float x) {
    __hip_bfloat16 h = __float2bfloat16(x);
    return __builtin_bit_cast(short, h);
}
// bf16-in-u32 unpack: lo16 -> f32 (bits<<16), hi16 -> f32 (bits & 0xFFFF0000)
static __device__ __forceinline__ float bf_lo(unsigned u) {
    return __builtin_bit_cast(float, u << 16);
}
static __device__ __forceinline__ float bf_hi(unsigned u) {
    return __builtin_bit_cast(float, u & 0xFFFF0000u);
}

// ---------------- prep: W1/W2 -> bf16 fragment-slot layout in ws -------------
// Per d: 24 slots x 128 s16x8 (49152 B).
//   slots 0..7  : W1^T (16 KB)   slots 8..23 : W2^T (32 KB)
// Entry j elems: bf16 of W[(kb+i)*128+j] (i=0..3) and W[(kb+16+i)*128+j] (4..7).
__global__ void rape_prep_kernel(const float* __restrict__ W1,
                                 const float* __restrict__ W2,
                                 s16x8* __restrict__ ws)
{
    const int d  = blockIdx.x / 24;
    const int sg = blockIdx.x % 24;
    const int j  = threadIdx.x;            // 0..127
    s16x8 v;
    if (sg < 8) {
        const float* W1d = W1 + (size_t)d * 65 * 128;
        const int kb = (sg >> 2) * 32 + (sg & 3) * 4;
        #pragma unroll
        for (int i = 0; i < 4; ++i) {
            v[i]     = f2bf(W1d[(kb + i) * 128 + j]);
            v[i + 4] = f2bf(W1d[(kb + 16 + i) * 128 + j]);
        }
    } else {
        const int sg2 = sg - 8;
        const float* W2d = W2 + (size_t)d * 128 * 128;
        const int kb = (sg2 >> 2) * 32 + (sg2 & 3) * 4;
        #pragma unroll
        for (int i = 0; i < 4; ++i) {
            v[i]     = f2bf(W2d[(kb + i) * 128 + j]);
            v[i + 4] = f2bf(W2d[(kb + 16 + i) * 128 + j]);
        }
    }
    ws[(size_t)d * 24 * 128 + sg * 128 + j] = v;
}

// ---------------- main fused kernel ------------------------------------------
// R5 shape (verified 244 us): 256 thr = 4 waves, 128 edges, es=2, 2 bar/d.
// R11 deltas: (1) W1 double-buffered — W1[d+1] issued after m1[d], drains at
// next bar1 (fully hidden), so bar2 drains only W2's 32 KB; (2) params packed
// as bf16 pairs (b1|w164, lnw|lnb) halving param LDS reads. LDS 75.5 KB.
__global__ __launch_bounds__(256, 2)
void rape_mfma11_kernel(const float* __restrict__ source,
                        const float* __restrict__ target,
                        const int*   __restrict__ edge,
                        const float* __restrict__ freqs,
                        const float* __restrict__ W1,
                        const float* __restrict__ b1,
                        const float* __restrict__ ln_w,
                        const float* __restrict__ ln_b,
                        const float* __restrict__ b2,
                        const s16x8* __restrict__ wsg,
                        float* __restrict__ out)
{
    __shared__ s16x8 w1buf[2][8 * 128];   // 2 x 16384 B (double-buffered)
    __shared__ s16x8 w2buf[16 * 128];     // 32768 B, restaged per d
    __shared__ float feat_s[6][128];      // 3072 B
    __shared__ unsigned b1w_s[768];       // lo=bf16(b1), hi=bf16(W1[64])  3072 B
    __shared__ unsigned lnwb_s[768];      // lo=bf16(ln_w), hi=bf16(ln_b)  3072 B
    __shared__ float freq_s[192];         // 768 B  -> total 75520 B

    const int tid   = threadIdx.x;
    const int lane  = tid & 63;
    const int wv    = tid >> 6;           // wave 0..3
    const int c     = lane & 15;          // edge-col within 16
    const int g     = lane >> 4;          // k-group 0..3
    const int ebase = blockIdx.x * 128;

    // ---- one-time staging: packed params + features ----
    for (int i = tid; i < 768; i += 256) {
        unsigned ub = (unsigned short)f2bf(b1[i]);
        unsigned uw = (unsigned short)f2bf(W1[((size_t)(i >> 7) * 65 + 64) * 128 + (i & 127)]);
        b1w_s[i] = ub | (uw << 16);
        unsigned ulw = (unsigned short)f2bf(ln_w[i]);
        unsigned ulb = (unsigned short)f2bf(ln_b[i]);
        lnwb_s[i] = ulw | (ulb << 16);
    }
    if (tid < 192) freq_s[tid] = freqs[tid];

    if (tid < 128) {
        int ec = ebase + tid; if (ec >= E_EDGES) ec = E_EDGES - 1;
        int si = edge[ec];
        int ti = edge[E_EDGES + ec];
        const float* S = source + (size_t)si * 5;
        const float* T = target + (size_t)ti * 5;
        float spx = S[0], spy = S[1], shd = S[2], ss = S[3];
        float tpx = T[0], tpy = T[1], thd = T[2], ts = T[3];
        float dx = spx - tpx, dy = spy - tpy;
        float dist = sqrtf(dx * dx + dy * dy);
        float ic  = dist < 3.0f ? 1.0f : 0.0f;
        float inv = dist > 0.0f ? 1.0f / dist : 0.0f;
        float ca  = dist > 0.0f ? dx * inv : 1.0f;   // cos(atan2), atan2(0,0)=0
        float sa  = dy * inv;
        float a = shd - thd + PI_F;
        float r = fmodf(a, TWOPI_F);
        r = r < 0.0f ? r + TWOPI_F : r;
        float dh = r - PI_F;
        float tc = ts * (cosf(thd) * ca + sinf(thd) * sa);
        float sc = ss * (cosf(shd) * ca + sinf(shd) * sa);
        feat_s[0][tid] = dx; feat_s[1][tid] = dy; feat_s[2][tid] = dh;
        feat_s[3][tid] = ic; feat_s[4][tid] = tc; feat_s[5][tid] = sc;
    }

    // ---- prologue: stage W1[0] -> w1buf[0] (drained by first bar1) ----
    {
        const char* gsrc = (const char*)wsg;          // d=0, slots 0..7
        #pragma unroll
        for (int it = 0; it < 4; ++it) {
            const int off = tid * 16 + it * 4096;
            __builtin_amdgcn_global_load_lds(
                (const __attribute__((address_space(1))) unsigned int*)(gsrc + off),
                (__attribute__((address_space(3))) unsigned int*)((char*)w1buf[0] + off),
                16, 0, 0);
        }
    }

    // ---- acc init: sum_d b2[d][g'],  g' = 4g + q + 16gt (global, once) ----
    f32x4 acc[2][8];
    #pragma unroll
    for (int gt = 0; gt < 8; ++gt) {
        f32x4 s = {0.f, 0.f, 0.f, 0.f};
        #pragma unroll
        for (int d = 0; d < 6; ++d)
            s += *(const f32x4*)(b2 + d * 128 + gt * 16 + g * 4);
        acc[0][gt] = s; acc[1][gt] = s;
    }

    for (int d = 0; d < 6; ++d) {
        // bar1: prev m2 done with w2buf; W1[d] stage drained (vmcnt0);
        // d=0: param/feat writes visible.
        __syncthreads();

        // ---- stage W2[d] -> w2buf (32 KB). Only these drain at bar2. ----
        {
            const char* gsrc = (const char*)(wsg + (size_t)d * 24 * 128) + 16384;
            #pragma unroll
            for (int it = 0; it < 8; ++it) {
                const int off = tid * 16 + it * 4096;
                __builtin_amdgcn_global_load_lds(
                    (const __attribute__((address_space(1))) unsigned int*)(gsrc + off),
                    (__attribute__((address_space(3))) unsigned int*)((char*)w2buf + off),
                    16, 0, 0);
            }
        }

        // ---- m1 B-frags from trig while W2 stages ----
        // k = 32*ks + 4g + q + 16p ; elem i<4 -> p=0, i>=4 -> p=1
        s16x8 bfr[2][2];
        float xv[2];
        const f32x4 fq0 = *(const f32x4*)(freq_s + d * 32 + g * 4);
        const f32x4 fq1 = *(const f32x4*)(freq_s + d * 32 + 16 + g * 4);
        #pragma unroll
        for (int es = 0; es < 2; ++es) {
            const float x = feat_s[d][wv * 32 + es * 16 + c];
            xv[es] = x;
            s16x8 bc, bs;
            #pragma unroll
            for (int i = 0; i < 8; ++i) {
                const float f = (i < 4) ? fq0[i] : fq1[i - 4];
                const float t = x * f;
                const float tf = t - floorf(t);
                bc[i] = f2bf(__builtin_amdgcn_cosf(tf));  // cos(2*pi*t)
                bs[i] = f2bf(__builtin_amdgcn_sinf(tf));
            }
            bfr[es][0] = bc; bfr[es][1] = bs;
        }

        // ---- d1 init: b1 + x * W1[k=64] (packed bf16 pair, fp32 math) ----
        f32x4 d1[2][8];
        #pragma unroll
        for (int jt = 0; jt < 8; ++jt) {
            const u32x4 pw = *(const u32x4*)(b1w_s + d * 128 + jt * 16 + g * 4);
            #pragma unroll
            for (int q = 0; q < 4; ++q) {
                const float bv  = bf_lo(pw[q]);
                const float wv4 = bf_hi(pw[q]);
                d1[0][jt][q] = fmaf(xv[0], wv4, bv);
                d1[1][jt][q] = fmaf(xv[1], wv4, bv);
            }
        }

        // bar2: W2[d] staged (vmcnt drained); w1buf[d&1] ready since bar1.
        __syncthreads();

        // ---- m1: D1'[j][e] += sum_{k<64} W1^T[j][k] * X^T[k][e] ----
        #pragma unroll
        for (int jt = 0; jt < 8; ++jt) {
            const s16x8 a0 = w1buf[d & 1][(0 + g) * 128 + jt * 16 + c];
            const s16x8 a1 = w1buf[d & 1][(4 + g) * 128 + jt * 16 + c];
            #pragma unroll
            for (int es = 0; es < 2; ++es) {
                d1[es][jt] = __builtin_amdgcn_mfma_f32_16x16x32_bf16(a0, bfr[es][0], d1[es][jt], 0, 0, 0);
                d1[es][jt] = __builtin_amdgcn_mfma_f32_16x16x32_bf16(a1, bfr[es][1], d1[es][jt], 0, 0, 0);
            }
        }

        // ---- prefetch W1[d+1] -> other buffer; drains at next bar1 ----
        // (w1buf[(d+1)&1] was last read at m1[d-1], before bar1[d] -> free.)
        if (d < 5) {
            const char* gsrc = (const char*)(wsg + (size_t)(d + 1) * 24 * 128);
            #pragma unroll
            for (int it = 0; it < 4; ++it) {
                const int off = tid * 16 + it * 4096;
                __builtin_amdgcn_global_load_lds(
                    (const __attribute__((address_space(1))) unsigned int*)(gsrc + off),
                    (__attribute__((address_space(3))) unsigned int*)((char*)w1buf[(d + 1) & 1] + off),
                    16, 0, 0);
            }
        }

        // ---- LayerNorm stats (lane holds j = 4g+q+16jt) ----
        float mu[2], rinv[2];
        #pragma unroll
        for (int es = 0; es < 2; ++es) {
            float s1 = 0.f, s2 = 0.f;
            #pragma unroll
            for (int jt = 0; jt < 8; ++jt)
                #pragma unroll
                for (int q = 0; q < 4; ++q) {
                    const float v = d1[es][jt][q];
                    s1 += v; s2 = fmaf(v, v, s2);
                }
            s1 += __shfl_xor(s1, 16); s1 += __shfl_xor(s1, 32);
            s2 += __shfl_xor(s2, 16); s2 += __shfl_xor(s2, 32);
            mu[es] = s1 * 0.0078125f;
            const float var = s2 * 0.0078125f - mu[es] * mu[es];
            rinv[es] = rsqrtf(var + 1e-5f);
        }

        // ---- LN apply + ReLU + pack (packed lnw/lnb, one read per jt) ----
        s16x8 pb[2][4];
        #pragma unroll
        for (int ks = 0; ks < 4; ++ks) {
            #pragma unroll
            for (int p = 0; p < 2; ++p) {
                const int jt = 2 * ks + p;
                const u32x4 lnp = *(const u32x4*)(lnwb_s + d * 128 + jt * 16 + g * 4);
                #pragma unroll
                for (int es = 0; es < 2; ++es) {
                    #pragma unroll
                    for (int q = 0; q < 4; ++q) {
                        const float lw = bf_lo(lnp[q]);
                        const float lb = bf_hi(lnp[q]);
                        float hv = (d1[es][jt][q] - mu[es]) * rinv[es];
                        hv = fmaf(hv, lw, lb);
                        hv = fmaxf(hv, 0.f);
                        pb[es][ks][q + 4 * p] = f2bf(hv);   // m2 B-frag (k=j)
                    }
                }
            }
        }

        // ---- m2: acc[g'][e] += sum_j W2^T[g'][j] * H'[j][e] ----
        #pragma unroll
        for (int ks = 0; ks < 4; ++ks) {
            #pragma unroll
            for (int gt = 0; gt < 8; ++gt) {
                const s16x8 a = w2buf[(ks * 4 + g) * 128 + gt * 16 + c];
                #pragma unroll
                for (int es = 0; es < 2; ++es)
                    acc[es][gt] = __builtin_amdgcn_mfma_f32_16x16x32_bf16(a, pb[es][ks], acc[es][gt], 0, 0, 0);
            }
        }
    }

    // ---- store: lane holds g' = 4g + q + 16gt of edges (wv*32 + es*16 + c) ----
    #pragma unroll
    for (int es = 0; es < 2; ++es) {
        const int e = ebase + wv * 32 + es * 16 + c;
        if (e < E_EDGES) {
            float* op = out + (size_t)e * 128 + g * 4;
            #pragma unroll
            for (int gt = 0; gt < 8; ++gt)
                *(f32x4*)(op + gt * 16) = acc[es][gt];
        }
    }
}

extern "C" void kernel_launch(void* const* d_in, const int* in_sizes, int n_in,
                              void* d_out, int out_size, void* d_ws, size_t ws_size,
                              hipStream_t stream) {
    const float* source = (const float*)d_in[0];
    const float* target = (const float*)d_in[1];
    const int*   edge   = (const int*)  d_in[2];
    const float* freqs  = (const float*)d_in[3];
    const float* W1     = (const float*)d_in[4];
    const float* b1     = (const float*)d_in[5];
    const float* ln_w   = (const float*)d_in[6];
    const float* ln_b   = (const float*)d_in[7];
    const float* W2     = (const float*)d_in[8];
    const float* b2     = (const float*)d_in[9];
    float* out = (float*)d_out;
    s16x8* wsg = (s16x8*)d_ws;    // needs 6*24*128*16 = 294912 B

    rape_prep_kernel<<<6 * 24, 128, 0, stream>>>(W1, W2, wsg);

    const int nblocks = (E_EDGES + 127) / 128;  // 3907
    rape_mfma11_kernel<<<nblocks, 256, 0, stream>>>(
        source, target, edge, freqs, W1, b1, ln_w, ln_b, b2, wsg, out);
}